// Round 7
// baseline (194.303 us; speedup 1.0000x reference)
//
#include <hip/hip_runtime.h>

// (B,P,C,H,W)=(256,10,32,8,8); Tm=19, Ta=10, hw=64. All I/O fp32.
// Horner: A_0=[F_0;1]; A_{p+1}=A_p*M_p+[F_{p+1};1] (p=0..8) -> A_9=[G;W]
// out[b,t,c,j] = (G[c,:].M_t[:,j]) / (W.M_t[:,j] + eps)
//
// R6 post-mortem: global-M per k-step + VGPR=64 serialized loads (VALU 14%).
// v7: phase 1 = R5's LDS-staged M + 2-way k-split (288 active threads, half
// the serial depth, same DS instr count); phase 2 = one wave per t, 8x4 lane
// tiles, M from global (DS work ~2.4x lower, weight-dot folded into m-quad).

#define EPSV 1e-6f

// A^T layout: element A[r][k] at k*40 + (r ^ swz(k)), swz = ((k>>2)&1)<<2.
// Quad r0..r0+3 (r0 % 4 == 0) stays contiguous & 16B-aligned.
__device__ __forceinline__ int at_off(int k, int r) {
    return k * 40 + (r ^ (((k >> 2) & 1) << 2));
}

__global__ __launch_bounds__(512, 1) void k_fused(
    const float* __restrict__ feats,   // (256,10,32,64)
    const float* __restrict__ sim,     // (256,19,64,64)
    float* __restrict__ out)           // (2560,32,64)
{
    __shared__ __attribute__((aligned(16))) float Mlds[2][4096];   // 32 KB dbuf
    __shared__ __attribute__((aligned(16))) float At[2][2560];     // 20 KB ping-pong
    __shared__ __attribute__((aligned(16))) float Pbuf[144 * 20];  // 11.25 KB partials

    const int tid  = threadIdx.x;
    const int b    = blockIdx.x;
    const float* fb = feats + (size_t)b * 20480;   // 10*32*64
    const float* sb = sim   + (size_t)b * 77824;   // 19*64*64

    // phase-1 compute coords: 288 workers = 2 k-halves x (9 rowquads x 16 colquads)
    const bool comp = tid < 288;
    const int h    = (tid >= 144) ? 1 : 0;   // k-half
    const int base = tid - h * 144;          // 0..143
    const int rg   = base >> 4;              // 0..8 (rg==8: rows 32..35 = [W;0;0;0])
    const int j0   = (base & 15) * 4;
    const int r0   = rg * 4;
    const int k0   = h * 32;

    // ---- init At[0] = [F_0; ones-row; zeros]^T (h==0 workers write) ----
    if (comp && h == 0) {
        float f[4][4];
        if (rg < 8) {
            #pragma unroll
            for (int i = 0; i < 4; ++i) {
                const float4 v = *(const float4*)&fb[(r0 + i) * 64 + j0];
                f[i][0] = v.x; f[i][1] = v.y; f[i][2] = v.z; f[i][3] = v.w;
            }
        } else {
            #pragma unroll
            for (int i = 0; i < 4; ++i)
                #pragma unroll
                for (int c = 0; c < 4; ++c) f[i][c] = (i == 0) ? 1.f : 0.f;
        }
        #pragma unroll
        for (int c = 0; c < 4; ++c) {
            float4 v; v.x = f[0][c]; v.y = f[1][c]; v.z = f[2][c]; v.w = f[3][c];
            *(float4*)&At[0][at_off(j0 + c, r0)] = v;
        }
    }
    // ---- stage M_0 (all 512 threads, 2 float4 each) ----
    {
        const float4 a = *(const float4*)&sb[tid * 4];
        const float4 c = *(const float4*)&sb[2048 + tid * 4];
        *(float4*)&Mlds[0][tid * 4] = a;
        *(float4*)&Mlds[0][2048 + tid * 4] = c;
    }
    __syncthreads();

    // ---- phase 1: 9 Horner steps, k-split 2-way ----
    for (int p = 0; p < 9; ++p) {
        const int cur = p & 1, nxt = cur ^ 1;

        float4 mst0, mst1;
        if (p < 8) {                         // global->reg prefetch of M_{p+1}
            mst0 = *(const float4*)&sb[(p + 1) * 4096 + tid * 4];
            mst1 = *(const float4*)&sb[(p + 1) * 4096 + 2048 + tid * 4];
        }
        float f[4][4];                       // F_{p+1} tile (h==0 only; issued early)
        if (comp && h == 0) {
            if (rg < 8) {
                #pragma unroll
                for (int i = 0; i < 4; ++i) {
                    const float4 v = *(const float4*)&fb[(p + 1) * 2048 + (r0 + i) * 64 + j0];
                    f[i][0] = v.x; f[i][1] = v.y; f[i][2] = v.z; f[i][3] = v.w;
                }
            } else {
                #pragma unroll
                for (int i = 0; i < 4; ++i)
                    #pragma unroll
                    for (int c = 0; c < 4; ++c) f[i][c] = (i == 0) ? 1.f : 0.f;
            }
        }

        float acc[16];
        if (comp) {
            #pragma unroll
            for (int i = 0; i < 16; ++i) acc[i] = 0.f;
            #pragma unroll 8
            for (int kk = 0; kk < 32; ++kk) {
                const int k = k0 + kk;
                const float4 a = *(const float4*)&At[cur][at_off(k, r0)];  // 4 rows @ col k
                const float4 m = *(const float4*)&Mlds[cur][k * 64 + j0];  // M[k][j0:+4]
                acc[0]  += a.x*m.x; acc[1]  += a.x*m.y; acc[2]  += a.x*m.z; acc[3]  += a.x*m.w;
                acc[4]  += a.y*m.x; acc[5]  += a.y*m.y; acc[6]  += a.y*m.z; acc[7]  += a.y*m.w;
                acc[8]  += a.z*m.x; acc[9]  += a.z*m.y; acc[10] += a.z*m.z; acc[11] += a.z*m.w;
                acc[12] += a.w*m.x; acc[13] += a.w*m.y; acc[14] += a.w*m.z; acc[15] += a.w*m.w;
            }
            if (h) {                         // publish upper-half partials
                #pragma unroll
                for (int q = 0; q < 4; ++q) {
                    float4 v; v.x = acc[q*4]; v.y = acc[q*4+1]; v.z = acc[q*4+2]; v.w = acc[q*4+3];
                    *(float4*)&Pbuf[base * 20 + q * 4] = v;
                }
            }
        }
        __syncthreads();                     // Pbuf ready; At[cur]/Mlds[cur] reads done

        if (comp && h == 0) {                // combine halves + F, write At[nxt]^T
            #pragma unroll
            for (int q = 0; q < 4; ++q) {
                const float4 v = *(const float4*)&Pbuf[base * 20 + q * 4];
                acc[q*4]   += v.x; acc[q*4+1] += v.y; acc[q*4+2] += v.z; acc[q*4+3] += v.w;
            }
            #pragma unroll
            for (int c = 0; c < 4; ++c) {
                float4 v;
                v.x = acc[0*4 + c] + f[0][c];
                v.y = acc[1*4 + c] + f[1][c];
                v.z = acc[2*4 + c] + f[2][c];
                v.w = acc[3*4 + c] + f[3][c];
                *(float4*)&At[nxt][at_off(j0 + c, r0)] = v;
            }
        }
        if (p < 8) {                         // spill M_{p+1} into the other buffer
            *(float4*)&Mlds[nxt][tid * 4] = mst0;
            *(float4*)&Mlds[nxt][2048 + tid * 4] = mst1;
        }
        __syncthreads();                     // At[nxt] + Mlds[nxt] ready
    }
    // At[1] = [G (32x64); W; 0]^T

    // ---- phase 2: one wave per t (8x4 lane tiles), M from global, no barriers ----
    const int wave = tid >> 6;
    const int lane = tid & 63;
    const int rr = (lane >> 4) * 8;          // 0,8,16,24
    const int jj = (lane & 15) * 4;
    const int njobs = (wave < 2) ? 2 : 1;

    for (int rep = 0; rep < njobs; ++rep) {
        const int t = wave + rep * 8;
        const float* __restrict__ Mt = sb + (9 + t) * 4096;

        float acc[32];
        #pragma unroll
        for (int i = 0; i < 32; ++i) acc[i] = 0.f;
        float wv0 = 0.f, wv1 = 0.f, wv2 = 0.f, wv3 = 0.f;

        #pragma unroll 8
        for (int k = 0; k < 64; ++k) {
            const float4 a0 = *(const float4*)&At[1][at_off(k, rr)];      // rows rr..+3
            const float4 a1 = *(const float4*)&At[1][at_off(k, rr + 4)];  // rows rr+4..+7
            const float  wk = At[1][at_off(k, 32)];                       // W[k], broadcast
            const float4 m  = *(const float4*)&Mt[k * 64 + jj];           // global b128
            wv0 += wk * m.x; wv1 += wk * m.y; wv2 += wk * m.z; wv3 += wk * m.w;
            acc[0]  += a0.x*m.x; acc[1]  += a0.x*m.y; acc[2]  += a0.x*m.z; acc[3]  += a0.x*m.w;
            acc[4]  += a0.y*m.x; acc[5]  += a0.y*m.y; acc[6]  += a0.y*m.z; acc[7]  += a0.y*m.w;
            acc[8]  += a0.z*m.x; acc[9]  += a0.z*m.y; acc[10] += a0.z*m.z; acc[11] += a0.z*m.w;
            acc[12] += a0.w*m.x; acc[13] += a0.w*m.y; acc[14] += a0.w*m.z; acc[15] += a0.w*m.w;
            acc[16] += a1.x*m.x; acc[17] += a1.x*m.y; acc[18] += a1.x*m.z; acc[19] += a1.x*m.w;
            acc[20] += a1.y*m.x; acc[21] += a1.y*m.y; acc[22] += a1.y*m.z; acc[23] += a1.y*m.w;
            acc[24] += a1.z*m.x; acc[25] += a1.z*m.y; acc[26] += a1.z*m.z; acc[27] += a1.z*m.w;
            acc[28] += a1.w*m.x; acc[29] += a1.w*m.y; acc[30] += a1.w*m.z; acc[31] += a1.w*m.w;
        }

        float4 rw;
        rw.x = 1.f / (wv0 + EPSV); rw.y = 1.f / (wv1 + EPSV);
        rw.z = 1.f / (wv2 + EPSV); rw.w = 1.f / (wv3 + EPSV);

        float* ob = out + ((size_t)b * 10 + t) * 2048;
        #pragma unroll
        for (int i = 0; i < 8; ++i) {
            float4 o;
            o.x = acc[i * 4 + 0] * rw.x;
            o.y = acc[i * 4 + 1] * rw.y;
            o.z = acc[i * 4 + 2] * rw.z;
            o.w = acc[i * 4 + 3] * rw.w;
            *(float4*)&ob[(rr + i) * 64 + jj] = o;
        }
    }
}

extern "C" void kernel_launch(void* const* d_in, const int* in_sizes, int n_in,
                              void* d_out, int out_size, void* d_ws, size_t ws_size,
                              hipStream_t stream) {
    const float* feats = (const float*)d_in[0];
    const float* sim   = (const float*)d_in[1];
    k_fused<<<256, 512, 0, stream>>>(feats, sim, (float*)d_out);
}

// Round 8
// 189.440 us; speedup vs baseline: 1.0257x; 1.0257x over previous
//
#include <hip/hip_runtime.h>

// (B,P,C,H,W)=(256,10,32,8,8); Tm=19, Ta=10, hw=64. All I/O fp32.
// Horner: A_0=[F_0;1]; A_{p+1}=A_p*M_p+[F_{p+1};1] (p=0..8) -> A_9=[G;W]
// out[b,t,c,j] = (G[c,:].M_t[:,j]) / (W.M_t[:,j] + eps)
//
// v8: phase 1 keeps A entirely in registers (wave w owns rows 4w..4w+3,
// lane j = col j; every wave carries its own W row). Cross-lane A[r,k] via
// v_readlane (VALU, no LDS, no barriers); M[k,:] via coalesced global b32
// (16KB M_p is L1-hot). ONE __syncthreads hands [G;W]^T to LDS, then R7's
// barrier-free phase 2 (1 wave/t, 8x4 tiles, M via global b128).

#define EPSV 1e-6f

__device__ __forceinline__ float rdlane(float v, int k) {
    return __int_as_float(__builtin_amdgcn_readlane(__float_as_int(v), k));
}

// G^T layout: element G[r][k] at k*40 + (r ^ swz(k)), swz = ((k>>2)&1)<<2.
// Quad r0..r0+3 (r0%4==0) contiguous & 16B-aligned; W row at r=32.
__device__ __forceinline__ int at_off(int k, int r) {
    return k * 40 + (r ^ (((k >> 2) & 1) << 2));
}

__global__ __launch_bounds__(512, 1) void k_fused(
    const float* __restrict__ feats,   // (256,10,32,64)
    const float* __restrict__ sim,     // (256,19,64,64)
    float* __restrict__ out)           // (2560,32,64)
{
    __shared__ __attribute__((aligned(16))) float At[2560];   // [G;W]^T, 10 KB

    const int tid  = threadIdx.x;
    const int lane = tid & 63;
    const int wave = tid >> 6;          // 0..7
    const int b    = blockIdx.x;

    const float* fb = feats + (size_t)b * 20480;   // 10*32*64
    const float* sb = sim   + (size_t)b * 77824;   // 19*64*64

    // ---- phase 1: registers only, no barriers ----
    const int r0 = wave * 4;
    float a0 = fb[(r0 + 0) * 64 + lane];
    float a1 = fb[(r0 + 1) * 64 + lane];
    float a2 = fb[(r0 + 2) * 64 + lane];
    float a3 = fb[(r0 + 3) * 64 + lane];
    float aw = 1.0f;                    // private W-row copy (redundant per wave)

    for (int p = 0; p < 9; ++p) {
        const float* __restrict__ M = sb + p * 4096;
        const float* __restrict__ F = fb + (p + 1) * 2048;

        const float f0 = F[(r0 + 0) * 64 + lane];
        const float f1 = F[(r0 + 1) * 64 + lane];
        const float f2 = F[(r0 + 2) * 64 + lane];
        const float f3 = F[(r0 + 3) * 64 + lane];

        float c0 = 0.f, c1 = 0.f, c2 = 0.f, c3 = 0.f, cw = 0.f;
        #pragma unroll 8
        for (int k = 0; k < 64; ++k) {
            const float m = M[k * 64 + lane];   // coalesced 256B row, L1-hot
            c0 += rdlane(a0, k) * m;
            c1 += rdlane(a1, k) * m;
            c2 += rdlane(a2, k) * m;
            c3 += rdlane(a3, k) * m;
            cw += rdlane(aw, k) * m;
        }
        a0 = c0 + f0; a1 = c1 + f1; a2 = c2 + f2; a3 = c3 + f3; aw = cw + 1.0f;
    }

    // ---- handoff: write [G;W]^T to LDS (one-time transposed writes) ----
    At[at_off(lane, r0 + 0)] = a0;
    At[at_off(lane, r0 + 1)] = a1;
    At[at_off(lane, r0 + 2)] = a2;
    At[at_off(lane, r0 + 3)] = a3;
    if (wave == 0) At[at_off(lane, 32)] = aw;
    __syncthreads();                    // the kernel's only barrier

    // ---- phase 2: one wave per t (8x4 lane tiles), M from global, no barriers ----
    const int rr = (lane >> 4) * 8;     // 0,8,16,24
    const int jj = (lane & 15) * 4;
    const int njobs = (wave < 2) ? 2 : 1;

    for (int rep = 0; rep < njobs; ++rep) {
        const int t = wave + rep * 8;
        const float* __restrict__ Mt = sb + (9 + t) * 4096;

        float acc[32];
        #pragma unroll
        for (int i = 0; i < 32; ++i) acc[i] = 0.f;
        float wv0 = 0.f, wv1 = 0.f, wv2 = 0.f, wv3 = 0.f;

        #pragma unroll 8
        for (int k = 0; k < 64; ++k) {
            const float4 g0 = *(const float4*)&At[at_off(k, rr)];      // rows rr..+3
            const float4 g1 = *(const float4*)&At[at_off(k, rr + 4)];  // rows rr+4..+7
            const float  wk = At[at_off(k, 32)];                       // W[k], broadcast
            const float4 m  = *(const float4*)&Mt[k * 64 + jj];        // global b128
            wv0 += wk * m.x; wv1 += wk * m.y; wv2 += wk * m.z; wv3 += wk * m.w;
            acc[0]  += g0.x*m.x; acc[1]  += g0.x*m.y; acc[2]  += g0.x*m.z; acc[3]  += g0.x*m.w;
            acc[4]  += g0.y*m.x; acc[5]  += g0.y*m.y; acc[6]  += g0.y*m.z; acc[7]  += g0.y*m.w;
            acc[8]  += g0.z*m.x; acc[9]  += g0.z*m.y; acc[10] += g0.z*m.z; acc[11] += g0.z*m.w;
            acc[12] += g0.w*m.x; acc[13] += g0.w*m.y; acc[14] += g0.w*m.z; acc[15] += g0.w*m.w;
            acc[16] += g1.x*m.x; acc[17] += g1.x*m.y; acc[18] += g1.x*m.z; acc[19] += g1.x*m.w;
            acc[20] += g1.y*m.x; acc[21] += g1.y*m.y; acc[22] += g1.y*m.z; acc[23] += g1.y*m.w;
            acc[24] += g1.z*m.x; acc[25] += g1.z*m.y; acc[26] += g1.z*m.z; acc[27] += g1.z*m.w;
            acc[28] += g1.w*m.x; acc[29] += g1.w*m.y; acc[30] += g1.w*m.z; acc[31] += g1.w*m.w;
        }

        float4 rw;
        rw.x = 1.f / (wv0 + EPSV); rw.y = 1.f / (wv1 + EPSV);
        rw.z = 1.f / (wv2 + EPSV); rw.w = 1.f / (wv3 + EPSV);

        float* ob = out + ((size_t)b * 10 + t) * 2048;
        #pragma unroll
        for (int i = 0; i < 8; ++i) {
            float4 o;
            o.x = acc[i * 4 + 0] * rw.x;
            o.y = acc[i * 4 + 1] * rw.y;
            o.z = acc[i * 4 + 2] * rw.z;
            o.w = acc[i * 4 + 3] * rw.w;
            *(float4*)&ob[(rr + i) * 64 + jj] = o;
        }
    }
}

extern "C" void kernel_launch(void* const* d_in, const int* in_sizes, int n_in,
                              void* d_out, int out_size, void* d_ws, size_t ws_size,
                              hipStream_t stream) {
    const float* feats = (const float*)d_in[0];
    const float* sim   = (const float*)d_in[1];
    k_fused<<<256, 512, 0, stream>>>(feats, sim, (float*)d_out);
}